// Round 5
// baseline (339.173 us; speedup 1.0000x reference)
//
#include <hip/hip_runtime.h>

// Fused RMSNorm(Q,K) + NeoX RoPE + V passthrough for packed QKV. All f32.
// Layout per token row (6144 f32): 32 Q heads x128 | 8 K heads x128 | 8 V x128.
// One block (256 thr) per token. 16-lane group per head; lane l owns the rope
// pair (x1[l*4..+4), x2[l*4..+4)) via two coalesced float4 loads, so the rope
// partner is lane-local. Only cross-lane op: 4x shfl_xor for the RMS sum.

namespace {

constexpr int kNumQ = 32;
constexpr int kNumK = 8;
constexpr int kHead = 128;
constexpr int kRow  = (kNumQ + 2 * kNumK) * kHead;  // 6144
constexpr int kHalf = 64;                            // rotary_dim/2
constexpr int kQK   = kNumQ + kNumK;                 // 40 heads get norm+rope

__global__ __launch_bounds__(256) void rope_qknorm_kernel(
    const float* __restrict__ qkv,
    const float* __restrict__ qw,
    const float* __restrict__ kw,
    const int* __restrict__ positions,
    float* __restrict__ out) {
  const int t   = blockIdx.x;
  const int tid = threadIdx.x;

  __shared__ float s_cos[kHalf];
  __shared__ float s_sin[kHalf];

  if (tid < kHalf) {
    // Mirror the reference's f32 chain: inv_freq = f32(1/10000^(i/64)),
    // phase = f32(pos * inv_freq), then accurate sin/cos of that f32 value
    // (double mod-2pi reduction; np.cos of the f32 arg is exact to ~1 ulp).
    const double log2b = 13.287712379549449629;  // log2(10000)
    float p = (float)exp2((double)tid * (log2b / 64.0));
    float inv_freq = 1.0f / p;
    float phase = (float)positions[t] * inv_freq;
    const double two_pi = 6.283185307179586476925286766559;
    float pr = (float)fmod((double)phase, two_pi);
    s_cos[tid] = cosf(pr);
    s_sin[tid] = sinf(pr);
  }
  __syncthreads();

  const int g = tid >> 4;   // head-group id in block (0..15)
  const int l = tid & 15;   // lane in group; owns rope-pair elems [l*4, l*4+4)

  const float* row  = qkv + (size_t)t * kRow;
  float*       orow = out + (size_t)t * kRow;

  const float4 cz = *reinterpret_cast<const float4*>(&s_cos[l * 4]);
  const float4 sz = *reinterpret_cast<const float4*>(&s_sin[l * 4]);

  const float4 qw1 = *reinterpret_cast<const float4*>(qw + l * 4);
  const float4 qw2 = *reinterpret_cast<const float4*>(qw + kHalf + l * 4);
  const float4 kw1 = *reinterpret_cast<const float4*>(kw + l * 4);
  const float4 kw2 = *reinterpret_cast<const float4*>(kw + kHalf + l * 4);

  #pragma unroll
  for (int hb = 0; hb < 48; hb += 16) {
    const int h = hb + g;                        // head index 0..47
    const float* hp = row + h * kHead + l * 4;
    const float4 a = *reinterpret_cast<const float4*>(hp);          // x1 frag
    const float4 b = *reinterpret_cast<const float4*>(hp + kHalf);  // x2 frag
    float* op = orow + h * kHead + l * 4;

    if (h < kQK) {                               // wave-uniform branch
      const bool isQ = (h < kNumQ);
      const float4 w1 = isQ ? qw1 : kw1;
      const float4 w2 = isQ ? qw2 : kw2;

      float ss = a.x * a.x + a.y * a.y + a.z * a.z + a.w * a.w +
                 b.x * b.x + b.y * b.y + b.z * b.z + b.w * b.w;
      #pragma unroll
      for (int m = 1; m < 16; m <<= 1) ss += __shfl_xor(ss, m, 16);
      const float inv = rsqrtf(ss * (1.0f / 128.0f) + 1e-6f);

      const float y1x = a.x * inv * w1.x, y1y = a.y * inv * w1.y;
      const float y1z = a.z * inv * w1.z, y1w = a.w * inv * w1.w;
      const float y2x = b.x * inv * w2.x, y2y = b.y * inv * w2.y;
      const float y2z = b.z * inv * w2.z, y2w = b.w * inv * w2.w;

      // out1 = y1*cos - y2*sin ; out2 = y2*cos + y1*sin
      float4 o1, o2;
      o1.x = y1x * cz.x - y2x * sz.x;
      o1.y = y1y * cz.y - y2y * sz.y;
      o1.z = y1z * cz.z - y2z * sz.z;
      o1.w = y1w * cz.w - y2w * sz.w;
      o2.x = y2x * cz.x + y1x * sz.x;
      o2.y = y2y * cz.y + y1y * sz.y;
      o2.z = y2z * cz.z + y1z * sz.z;
      o2.w = y2w * cz.w + y1w * sz.w;
      *reinterpret_cast<float4*>(op)         = o1;
      *reinterpret_cast<float4*>(op + kHalf) = o2;
    } else {
      // V heads: bit-exact passthrough.
      *reinterpret_cast<float4*>(op)         = a;
      *reinterpret_cast<float4*>(op + kHalf) = b;
    }
  }
}

}  // namespace

extern "C" void kernel_launch(void* const* d_in, const int* in_sizes, int n_in,
                              void* d_out, int out_size, void* d_ws, size_t ws_size,
                              hipStream_t stream) {
  const float* qkv     = (const float*)d_in[0];
  const float* qw      = (const float*)d_in[1];
  const float* kw      = (const float*)d_in[2];
  const int* positions = (const int*)d_in[3];
  float* out           = (float*)d_out;

  const int tokens = in_sizes[3];  // positions element count == NUM_TOKENS
  rope_qknorm_kernel<<<tokens, 256, 0, stream>>>(qkv, qw, kw, positions, out);
}